// Round 1
// baseline (5006.492 us; speedup 1.0000x reference)
//
#include <hip/hip_runtime.h>
#include <stdint.h>

#define NQ 2048
#define NT 65536
#define DIM 512
#define KNN 32
#define NC 100

#define QT 64              // queries per block
#define NSLICE 32          // train slices
#define SLICE (NT / NSLICE) // 2048 trains per slice
#define TT 128             // train chunk per iteration
#define KK 32              // k-dim chunk

// ---------------- row-norm kernel: one wave per row (512 floats) ----------------
__global__ void norm_kernel(const float* __restrict__ X, float* __restrict__ out, int nrows) {
    int row = blockIdx.x * 4 + (threadIdx.x >> 6);
    int lane = threadIdx.x & 63;
    if (row >= nrows) return;
    const float4* p = (const float4*)(X + (size_t)row * DIM);
    float4 a = p[lane];
    float4 b = p[lane + 64];
    float s = a.x*a.x + a.y*a.y + a.z*a.z + a.w*a.w
            + b.x*b.x + b.y*b.y + b.z*b.z + b.w*b.w;
    #pragma unroll
    for (int off = 32; off > 0; off >>= 1) s += __shfl_down(s, off, 64);
    if (lane == 0) out[row] = s;
}

// ---------------- fused distance + per-slice top-K ----------------
// grid: (NQ/QT, NSLICE); block: 256
// cand layout: cand[q][slice][k]  (uint64 keys, sorted ascending per slice)
__launch_bounds__(256, 2)
__global__ void knn_part(const float* __restrict__ Xq, const float* __restrict__ Xt,
                         const float* __restrict__ q2, const float* __restrict__ t2,
                         unsigned long long* __restrict__ cand) {
    __shared__ float sQ[KK][QT];                 // 8 KB  (k-major)
    __shared__ float sT[KK][TT];                 // 16 KB (k-major)
    __shared__ float sD[QT][TT + 1];             // 33 KB (padded: conflict-free row scan)
    __shared__ unsigned long long topk[QT][KNN + 1]; // 16.5 KB (padded rows)

    const int tid = threadIdx.x;
    const int q0 = blockIdx.x * QT;
    const int t0 = blockIdx.y * SLICE;

    for (int i = tid; i < QT * (KNN + 1); i += 256)
        ((unsigned long long*)topk)[i] = ~0ULL;

    const int tq = tid >> 4;   // 0..15 -> queries tq*4 .. tq*4+3
    const int tt = tid & 15;   // 0..15 -> trains  tt*8 .. tt*8+7

    const int lq = tid >> 3;        // 0..31 (staging loads)
    const int kg = (tid & 7) * 4;   // 0,4,...,28

    unsigned long long kth = ~0ULL; // cached 32nd-best key (selection threads only)

    for (int chunk = 0; chunk < SLICE / TT; ++chunk) {
        float acc[4][8];
        #pragma unroll
        for (int i = 0; i < 4; ++i)
            #pragma unroll
            for (int j = 0; j < 8; ++j) acc[i][j] = 0.f;

        const float* Tc = Xt + (size_t)(t0 + chunk * TT) * DIM;

        for (int k0 = 0; k0 < DIM; k0 += KK) {
            __syncthreads();  // protect sQ/sT (and sD from previous chunk's selection)
            // stage Q tile (transposed): rows lq and lq+32
            {
                float4 v0 = *(const float4*)(Xq + (size_t)(q0 + lq) * DIM + k0 + kg);
                float4 v1 = *(const float4*)(Xq + (size_t)(q0 + lq + 32) * DIM + k0 + kg);
                sQ[kg + 0][lq] = v0.x; sQ[kg + 1][lq] = v0.y;
                sQ[kg + 2][lq] = v0.z; sQ[kg + 3][lq] = v0.w;
                sQ[kg + 0][lq + 32] = v1.x; sQ[kg + 1][lq + 32] = v1.y;
                sQ[kg + 2][lq + 32] = v1.z; sQ[kg + 3][lq + 32] = v1.w;
            }
            // stage T tile (transposed): rows lq + 32*rr
            #pragma unroll
            for (int rr = 0; rr < 4; ++rr) {
                int r = lq + rr * 32;
                float4 v = *(const float4*)(Tc + (size_t)r * DIM + k0 + kg);
                sT[kg + 0][r] = v.x; sT[kg + 1][r] = v.y;
                sT[kg + 2][r] = v.z; sT[kg + 3][r] = v.w;
            }
            __syncthreads();

            #pragma unroll 8
            for (int k = 0; k < KK; ++k) {
                float4 qv = *(const float4*)&sQ[k][tq << 2];
                float4 ta = *(const float4*)&sT[k][tt << 3];
                float4 tb = *(const float4*)&sT[k][(tt << 3) + 4];
                float qa[4] = {qv.x, qv.y, qv.z, qv.w};
                float tv[8] = {ta.x, ta.y, ta.z, ta.w, tb.x, tb.y, tb.z, tb.w};
                #pragma unroll
                for (int i = 0; i < 4; ++i)
                    #pragma unroll
                    for (int j = 0; j < 8; ++j)
                        acc[i][j] = fmaf(qa[i], tv[j], acc[i][j]);
            }
        }

        // epilogue: d2 = max(q2 + t2 - 2*dot, 0) -> sD
        #pragma unroll
        for (int i = 0; i < 4; ++i) {
            float qq = q2[q0 + (tq << 2) + i];
            #pragma unroll
            for (int j = 0; j < 8; ++j) {
                int t = (tt << 3) + j;
                float d = (qq - 2.f * acc[i][j]) + t2[t0 + chunk * TT + t];
                sD[(tq << 2) + i][t] = fmaxf(d, 0.f);
            }
        }
        __syncthreads();

        // selection: thread q (< 64) scans its row, maintains sorted top-32
        if (tid < QT) {
            int gbase = t0 + chunk * TT;
            for (int t = 0; t < TT; ++t) {
                float d = sD[tid][t];
                unsigned long long key =
                    ((unsigned long long)__float_as_uint(d) << 16) |
                    (unsigned long long)((gbase + t) & 0xFFFF);
                if (key < kth) {
                    int j = KNN - 1;
                    while (j > 0 && topk[tid][j - 1] > key) {
                        topk[tid][j] = topk[tid][j - 1];
                        --j;
                    }
                    topk[tid][j] = key;
                    kth = topk[tid][KNN - 1];
                }
            }
        }
        // no barrier needed here: next chunk's first k-loop barrier orders
        // selection (reads sD) before the next epilogue writes sD.
    }

    __syncthreads();
    for (int i = tid; i < QT * KNN; i += 256) {
        int q = i >> 5, k = i & 31;
        cand[((size_t)(q0 + q) * NSLICE + blockIdx.y) * KNN + k] = topk[q][k];
    }
}

// ---------------- merge + vote: one block per query ----------------
__global__ void knn_merge(const unsigned long long* __restrict__ cand,
                          const int* __restrict__ y_train, int* __restrict__ out) {
    __shared__ unsigned long long keys[NSLICE * KNN]; // 8 KB
    __shared__ unsigned long long top[KNN];
    __shared__ int counts[NC];
    int q = blockIdx.x;
    for (int i = threadIdx.x; i < NSLICE * KNN; i += 64)
        keys[i] = cand[(size_t)q * NSLICE * KNN + i];
    for (int i = threadIdx.x; i < NC; i += 64) counts[i] = 0;
    if (threadIdx.x < KNN) top[threadIdx.x] = ~0ULL;
    __syncthreads();

    if (threadIdx.x == 0) {
        // exact global top-32: each slice list is sorted ascending -> early break
        for (int s = 0; s < NSLICE; ++s) {
            for (int j = 0; j < KNN; ++j) {
                unsigned long long key = keys[s * KNN + j];
                if (key >= top[KNN - 1]) break;
                int p = KNN - 1;
                while (p > 0 && top[p - 1] > key) { top[p] = top[p - 1]; --p; }
                top[p] = key;
            }
        }
        // majority vote, argmax with lowest-class tie-break
        for (int k = 0; k < KNN; ++k) {
            int idx = (int)(top[k] & 0xFFFF);
            counts[y_train[idx]]++;
        }
        int bestc = counts[0], bestl = 0;
        for (int c = 1; c < NC; ++c) {
            if (counts[c] > bestc) { bestc = counts[c]; bestl = c; }
        }
        out[q] = bestl;
    }
}

extern "C" void kernel_launch(void* const* d_in, const int* in_sizes, int n_in,
                              void* d_out, int out_size, void* d_ws, size_t ws_size,
                              hipStream_t stream) {
    const float* Xq = (const float*)d_in[0];   // [2048, 512]
    const float* Xt = (const float*)d_in[1];   // [65536, 512]
    const int*   y  = (const int*)d_in[2];     // [65536]
    int* out = (int*)d_out;                    // [2048] int32

    float* t2 = (float*)d_ws;                  // 65536 floats
    float* q2 = t2 + NT;                       // 2048 floats
    unsigned long long* cand =
        (unsigned long long*)((char*)d_ws + (size_t)(NT + NQ) * sizeof(float)); // 16 MB

    norm_kernel<<<NT / 4, 256, 0, stream>>>(Xt, t2, NT);
    norm_kernel<<<NQ / 4, 256, 0, stream>>>(Xq, q2, NQ);
    knn_part<<<dim3(NQ / QT, NSLICE), 256, 0, stream>>>(Xq, Xt, q2, t2, cand);
    knn_merge<<<NQ, 64, 0, stream>>>(cand, y, out);
}

// Round 2
// 3212.980 us; speedup vs baseline: 1.5582x; 1.5582x over previous
//
#include <hip/hip_runtime.h>
#include <stdint.h>

#define NQ 2048
#define NT 65536
#define DIM 512
#define KNN 32
#define NC 100

#define QT 32               // queries per block
#define NSLICE 32           // train slices
#define SLICE (NT / NSLICE) // 2048 trains per slice
#define TT 256              // train chunk per selection round
#define KK 16               // k-dim staging chunk
#define CAP 32              // candidate buffer capacity per query per pass

// ---------------- row-norm kernel: one wave per row (512 floats) ----------------
__global__ void norm_kernel(const float* __restrict__ X, float* __restrict__ out, int nrows) {
    int row = blockIdx.x * 4 + (threadIdx.x >> 6);
    int lane = threadIdx.x & 63;
    if (row >= nrows) return;
    const float4* p = (const float4*)(X + (size_t)row * DIM);
    float4 a = p[lane];
    float4 b = p[lane + 64];
    float s = a.x*a.x + a.y*a.y + a.z*a.z + a.w*a.w
            + b.x*b.x + b.y*b.y + b.z*b.z + b.w*b.w;
    #pragma unroll
    for (int off = 32; off > 0; off >>= 1) s += __shfl_down(s, off, 64);
    if (lane == 0) out[row] = s;
}

// ---------------- fused distance + per-slice top-K (filter-based) ----------------
// grid: (NQ/QT, NSLICE); block: 256
// cand layout: cand[q][slice][k]  (uint64 keys, sorted ascending per slice)
__launch_bounds__(256, 4)
__global__ void knn_part(const float* __restrict__ Xq, const float* __restrict__ Xt,
                         const float* __restrict__ q2, const float* __restrict__ t2,
                         unsigned long long* __restrict__ cand) {
    __shared__ float sQ[KK][QT];                       // 2 KB   (k-major)
    __shared__ float sT[KK][TT];                       // 16 KB  (k-major)
    __shared__ unsigned long long topk[QT][KNN];       // 8 KB
    __shared__ unsigned long long buf[QT][CAP];        // 8 KB
    __shared__ unsigned long long kth64[QT];           // 256 B
    __shared__ unsigned int cnt[QT];                   // 128 B
    __shared__ int againF;

    const int tid = threadIdx.x;
    const int q0 = blockIdx.x * QT;
    const int t0 = blockIdx.y * SLICE;

    // micro-tile: 4 queries x (4+4) trains per thread
    const int tq4 = (tid >> 5) * 4;   // query group base (0..28)
    const int tt4 = (tid & 31) * 4;   // train group base within first half (0..124)

    // staging maps
    const int pg = tid & 63;          // sT: loads rows pg*4 .. pg*4+3
    const int kg = tid >> 6;          // sT: k-offset kg*4
    const int qp = tid & 31;          // sQ: query row
    const int kq = tid >> 5;          // sQ: k-offset kq*2

    // init
    for (int i = tid; i < QT * KNN; i += 256)
        ((unsigned long long*)topk)[i] = ~0ULL;
    if (tid < QT) { kth64[tid] = ~0ULL; cnt[tid] = 0u; }
    if (tid == 0) againF = 0;

    float qq[4];
    #pragma unroll
    for (int i = 0; i < 4; ++i) qq[i] = q2[q0 + tq4 + i];

    for (int chunk = 0; chunk < SLICE / TT; ++chunk) {
        const int tbase = t0 + chunk * TT;
        float acc[4][8];
        #pragma unroll
        for (int i = 0; i < 4; ++i)
            #pragma unroll
            for (int j = 0; j < 8; ++j) acc[i][j] = 0.f;

        for (int k0 = 0; k0 < DIM; k0 += KK) {
            __syncthreads();   // previous tile fully consumed / init visible
            // --- stage T tile (256 pts x 16 k), register transpose, b128 writes ---
            {
                const float* Tp = Xt + (size_t)(tbase + pg * 4) * DIM + k0 + kg * 4;
                float4 r0 = *(const float4*)(Tp);
                float4 r1 = *(const float4*)(Tp + DIM);
                float4 r2 = *(const float4*)(Tp + 2 * DIM);
                float4 r3 = *(const float4*)(Tp + 3 * DIM);
                *(float4*)&sT[kg * 4 + 0][pg * 4] = make_float4(r0.x, r1.x, r2.x, r3.x);
                *(float4*)&sT[kg * 4 + 1][pg * 4] = make_float4(r0.y, r1.y, r2.y, r3.y);
                *(float4*)&sT[kg * 4 + 2][pg * 4] = make_float4(r0.z, r1.z, r2.z, r3.z);
                *(float4*)&sT[kg * 4 + 3][pg * 4] = make_float4(r0.w, r1.w, r2.w, r3.w);
            }
            // --- stage Q tile (32 pts x 16 k) ---
            {
                float2 v = *(const float2*)(Xq + (size_t)(q0 + qp) * DIM + k0 + kq * 2);
                sQ[kq * 2 + 0][qp] = v.x;
                sQ[kq * 2 + 1][qp] = v.y;
            }
            __syncthreads();

            // --- FMA inner loop: conflict-free b128 fragment reads ---
            #pragma unroll
            for (int k = 0; k < KK; ++k) {
                float4 qv = *(const float4*)&sQ[k][tq4];
                float4 ta = *(const float4*)&sT[k][tt4];
                float4 tb = *(const float4*)&sT[k][128 + tt4];
                float qa[4] = {qv.x, qv.y, qv.z, qv.w};
                float tv[8] = {ta.x, ta.y, ta.z, ta.w, tb.x, tb.y, tb.z, tb.w};
                #pragma unroll
                for (int i = 0; i < 4; ++i)
                    #pragma unroll
                    for (int j = 0; j < 8; ++j)
                        acc[i][j] = fmaf(qa[i], tv[j], acc[i][j]);
            }
        }

        // --- epilogue: acc <- d2 = max(q2 - 2*dot + t2, 0) ---
        float t2v[8];
        #pragma unroll
        for (int j = 0; j < 4; ++j) {
            t2v[j]     = t2[tbase + tt4 + j];
            t2v[4 + j] = t2[tbase + 128 + tt4 + j];
        }
        #pragma unroll
        for (int i = 0; i < 4; ++i)
            #pragma unroll
            for (int j = 0; j < 8; ++j)
                acc[i][j] = fmaxf((qq[i] - 2.f * acc[i][j]) + t2v[j], 0.f);

        // --- selection: threshold filter + compact buffer, overflow-safe ---
        unsigned mask = 0;
        for (;;) {
            unsigned long long kv[4];
            #pragma unroll
            for (int i = 0; i < 4; ++i) kv[i] = kth64[tq4 + i];
            #pragma unroll
            for (int i = 0; i < 4; ++i) {
                #pragma unroll
                for (int j = 0; j < 8; ++j) {
                    unsigned b = 1u << (i * 8 + j);
                    if (mask & b) continue;
                    int tloc = (j < 4) ? (tt4 + j) : (128 + tt4 + (j - 4));
                    unsigned long long key =
                        ((unsigned long long)__float_as_uint(acc[i][j]) << 16) |
                        (unsigned long long)(unsigned)(tbase + tloc);
                    if (key < kv[i]) {
                        unsigned pos = atomicAdd(&cnt[tq4 + i], 1u);
                        if (pos < CAP) { buf[tq4 + i][pos] = key; mask |= b; }
                    }
                }
            }
            __syncthreads();   // buf/cnt complete
            if (tid < QT) {
                unsigned n = cnt[tid];
                unsigned m = n < CAP ? n : CAP;
                for (unsigned e = 0; e < m; ++e) {
                    unsigned long long key = buf[tid][e];
                    if (key < topk[tid][KNN - 1]) {
                        int p = KNN - 1;
                        while (p > 0 && topk[tid][p - 1] > key) {
                            topk[tid][p] = topk[tid][p - 1];
                            --p;
                        }
                        topk[tid][p] = key;
                    }
                }
                kth64[tid] = topk[tid][KNN - 1];
                if (n > CAP) againF = 1;   // benign race: all writers store 1
                cnt[tid] = 0u;
            }
            __syncthreads();   // insert done, againF final, kth updated
            int go = againF;
            __syncthreads();   // all reads of againF done
            if (tid == 0) againF = 0;
            if (!go) break;    // uniform
            __syncthreads();   // reset + kth visible before next filter pass
        }
    }

    __syncthreads();
    for (int i = tid; i < QT * KNN; i += 256) {
        int q = i >> 5, k = i & 31;
        cand[((size_t)(q0 + q) * NSLICE + blockIdx.y) * KNN + k] = topk[q][k];
    }
}

// ---------------- merge + vote: one block per query ----------------
__global__ void knn_merge(const unsigned long long* __restrict__ cand,
                          const int* __restrict__ y_train, int* __restrict__ out) {
    __shared__ unsigned long long keys[NSLICE * KNN]; // 8 KB
    __shared__ unsigned long long top[KNN];
    __shared__ int counts[NC];
    int q = blockIdx.x;
    for (int i = threadIdx.x; i < NSLICE * KNN; i += 64)
        keys[i] = cand[(size_t)q * NSLICE * KNN + i];
    for (int i = threadIdx.x; i < NC; i += 64) counts[i] = 0;
    if (threadIdx.x < KNN) top[threadIdx.x] = ~0ULL;
    __syncthreads();

    if (threadIdx.x == 0) {
        for (int s = 0; s < NSLICE; ++s) {
            for (int j = 0; j < KNN; ++j) {
                unsigned long long key = keys[s * KNN + j];
                if (key >= top[KNN - 1]) break;   // sorted slice list -> early out
                int p = KNN - 1;
                while (p > 0 && top[p - 1] > key) { top[p] = top[p - 1]; --p; }
                top[p] = key;
            }
        }
        for (int k = 0; k < KNN; ++k) {
            int idx = (int)(top[k] & 0xFFFF);
            counts[y_train[idx]]++;
        }
        int bestc = counts[0], bestl = 0;
        for (int c = 1; c < NC; ++c)
            if (counts[c] > bestc) { bestc = counts[c]; bestl = c; }
        out[q] = bestl;
    }
}

extern "C" void kernel_launch(void* const* d_in, const int* in_sizes, int n_in,
                              void* d_out, int out_size, void* d_ws, size_t ws_size,
                              hipStream_t stream) {
    const float* Xq = (const float*)d_in[0];   // [2048, 512]
    const float* Xt = (const float*)d_in[1];   // [65536, 512]
    const int*   y  = (const int*)d_in[2];     // [65536]
    int* out = (int*)d_out;                    // [2048] int32

    float* t2 = (float*)d_ws;                  // 65536 floats
    float* q2 = t2 + NT;                       // 2048 floats
    unsigned long long* cand =
        (unsigned long long*)((char*)d_ws + (size_t)(NT + NQ) * sizeof(float)); // 16.8 MB

    norm_kernel<<<NT / 4, 256, 0, stream>>>(Xt, t2, NT);
    norm_kernel<<<NQ / 4, 256, 0, stream>>>(Xq, q2, NQ);
    knn_part<<<dim3(NQ / QT, NSLICE), 256, 0, stream>>>(Xq, Xt, q2, t2, cand);
    knn_merge<<<NQ, 64, 0, stream>>>(cand, y, out);
}